// Round 1
// baseline (90.787 us; speedup 1.0000x reference)
//
#include <hip/hip_runtime.h>
#include <hip/hip_bf16.h>

// Problem: B=512, D=256, M=256, TEMP=0.07
//   anchor = features_o[mask_sents]            [M,D]
//   sim    = anchor @ features_i^T / TEMP      [M,B]
//   loss_sum = sum_m sum_{p in pos(m)} sum_{n in neg(m)} softplus(sim[m,n]-sim[m,p])
//   pair_num = sum_m |pos(m)|*|neg(m)|
//   loss = pair_num>0 ? loss_sum/pair_num : loss_sum
//
// Workspace layout (d_ws):
//   [0]   float    loss_sum accumulator
//   [1]   uint32   pair_num accumulator
//   +256B float    sim[M*B]  (512 KB)

#define BDIM 512
#define MDIM 256
#define DDIM 256
#define INV_TEMP (1.0f / 0.07f)

// ---------------- Kernel 1: sim = features_o[sents] @ features_i^T / TEMP ----
__global__ __launch_bounds__(256) void sim_kernel(
        const float* __restrict__ fo, const float* __restrict__ fi,
        const int* __restrict__ sents, float* __restrict__ sim) {
    __shared__ float As[32][33];
    __shared__ float Bs[32][33];
    __shared__ int rowIdx[32];
    const int tid = threadIdx.x;
    const int m0 = blockIdx.y * 32;
    const int n0 = blockIdx.x * 32;
    if (tid < 32) rowIdx[tid] = sents[m0 + tid];
    __syncthreads();
    const int tx = tid & 15, ty = tid >> 4;
    float a00 = 0.f, a01 = 0.f, a10 = 0.f, a11 = 0.f;
    for (int k0 = 0; k0 < DDIM; k0 += 32) {
#pragma unroll
        for (int i = 0; i < 4; ++i) {
            int idx = tid + i * 256;
            int r = idx >> 5, c = idx & 31;
            As[r][c] = fo[rowIdx[r] * DDIM + k0 + c];
            Bs[r][c] = fi[(n0 + r) * DDIM + k0 + c];
        }
        __syncthreads();
#pragma unroll
        for (int k = 0; k < 32; ++k) {
            float av0 = As[ty][k],     av1 = As[ty + 16][k];
            float bv0 = Bs[tx][k],     bv1 = Bs[tx + 16][k];
            a00 = fmaf(av0, bv0, a00);
            a01 = fmaf(av0, bv1, a01);
            a10 = fmaf(av1, bv0, a10);
            a11 = fmaf(av1, bv1, a11);
        }
        __syncthreads();
    }
    sim[(m0 + ty) * BDIM + n0 + tx]           = a00 * INV_TEMP;
    sim[(m0 + ty) * BDIM + n0 + tx + 16]      = a01 * INV_TEMP;
    sim[(m0 + ty + 16) * BDIM + n0 + tx]      = a10 * INV_TEMP;
    sim[(m0 + ty + 16) * BDIM + n0 + tx + 16] = a11 * INV_TEMP;
}

// ---------------- Kernel 2: pairwise softplus loss ---------------------------
// grid = 2*M blocks (two blocks share one row m, splitting the pos-axis),
// 512 threads arranged as a 32(n) x 16(p-local) virtual grid.
__global__ __launch_bounds__(512) void loss_kernel(
        const float* __restrict__ sim, const float* __restrict__ mask,
        const int* __restrict__ sents, float* __restrict__ ws) {
    __shared__ float s_psim[BDIM];
    __shared__ float s_nsim[BDIM];
    __shared__ int s_wcnt[8];
    __shared__ float s_red[8];

    const int tid  = threadIdx.x;
    const int lane = tid & 63;
    const int wave = tid >> 6;
    const int m    = blockIdx.x >> 1;
    const int half = blockIdx.x & 1;

    const int srow = sents[m];
    const float simval = sim[m * BDIM + tid];
    const float mv = mask[srow * BDIM + tid];
    const bool flag = (mv > 0.5f);

    // deterministic ballot-based compaction (both twin blocks produce
    // identical s_psim / s_nsim orderings)
    unsigned long long bal = __ballot(flag);
    int below = __popcll(bal & ((1ull << lane) - 1ull));
    if (lane == 0) s_wcnt[wave] = __popcll(bal);
    __syncthreads();
    int base_pos = 0, np = 0;
#pragma unroll
    for (int w = 0; w < 8; ++w) {
        int c = s_wcnt[w];
        if (w < wave) base_pos += c;
        np += c;
    }
    const int nn = BDIM - np;
    const int base_neg = wave * 64 - base_pos;
    if (flag) s_psim[base_pos + below]          = simval;
    else      s_nsim[base_neg + (lane - below)] = simval;
    __syncthreads();

    // pair loop: virtual 32x32 grid over (n, p)
    const int tn  = tid & 31;
    const int tp  = half * 16 + (tid >> 5);   // 0..31
    float acc = 0.f;
    if (np > 0 && nn > 0) {
        for (int jp = tp; jp < np; jp += 32) {
            const float sp = s_psim[jp];
            for (int jn = tn; jn < nn; jn += 32) {
                float x = s_nsim[jn] - sp;            // sim_n - sim_p
                float e = __expf(-fabsf(x));
                acc += fmaxf(x, 0.f) + __logf(1.f + e);
            }
        }
    }

    // block reduction
#pragma unroll
    for (int off = 32; off > 0; off >>= 1) acc += __shfl_down(acc, off);
    if (lane == 0) s_red[wave] = acc;
    __syncthreads();
    if (tid == 0) {
        float bs = 0.f;
#pragma unroll
        for (int w = 0; w < 8; ++w) bs += s_red[w];
        atomicAdd(&ws[0], bs);
        if (half == 0) atomicAdd((unsigned int*)ws + 1, (unsigned int)(np * nn));
    }
}

// ---------------- Kernel 3: finalize -----------------------------------------
__global__ void finalize_kernel(const float* __restrict__ ws,
                                float* __restrict__ out) {
    float ls = ws[0];
    unsigned int pn = ((const unsigned int*)ws)[1];
    out[0] = (pn > 0u) ? (ls / (float)pn) : ls;
}

extern "C" void kernel_launch(void* const* d_in, const int* in_sizes, int n_in,
                              void* d_out, int out_size, void* d_ws, size_t ws_size,
                              hipStream_t stream) {
    const float* fo    = (const float*)d_in[0];   // [512,256]
    const float* fi    = (const float*)d_in[1];   // [512,256]
    const float* mask  = (const float*)d_in[2];   // [512,512]
    const int*   sents = (const int*)d_in[3];     // [256]
    float* out = (float*)d_out;

    float* ws  = (float*)d_ws;                    // accumulators
    float* sim = (float*)((char*)d_ws + 256);     // 512 KB sim buffer

    // zero the accumulators (d_ws is re-poisoned before every timed launch)
    hipMemsetAsync(d_ws, 0, 8, stream);

    dim3 grid1(BDIM / 32, MDIM / 32);             // (16, 8)
    sim_kernel<<<grid1, 256, 0, stream>>>(fo, fi, sents, sim);

    loss_kernel<<<2 * MDIM, 512, 0, stream>>>(sim, mask, sents, ws);

    finalize_kernel<<<1, 1, 0, stream>>>(ws, out);
}